// Round 5
// baseline (742.306 us; speedup 1.0000x reference)
//
#include <hip/hip_runtime.h>
#include <hip/hip_bf16.h>

// Sizes fixed by the problem.
#define BS    64
#define KDIM  256   // in_dim
#define ICAP  256   // I = 16*16
#define JCAP  64    // J out-caps
#define D2    32
#define OUTD  2048  // J*D2
#define PART  64    // partial-sum chunks for route passes (4 i per chunk)

typedef short bf16x8 __attribute__((ext_vector_type(8)));
typedef float f32x4  __attribute__((ext_vector_type(4)));

static __device__ __forceinline__ float bf2f(unsigned u16) {
  union { unsigned u; float f; } v; v.u = u16 << 16; return v.f;
}
static __device__ __forceinline__ unsigned short f2bf(float x) {
  union { float f; unsigned u; } v; v.f = x;
  unsigned r = v.u + 0x7fffu + ((v.u >> 16) & 1u);
  return (unsigned short)(r >> 16);
}
static __device__ __forceinline__ void unpack8(uint4 u, float* f) {
  f[0] = bf2f(u.x & 0xffffu); f[1] = bf2f(u.x >> 16);
  f[2] = bf2f(u.y & 0xffffu); f[3] = bf2f(u.y >> 16);
  f[4] = bf2f(u.z & 0xffffu); f[5] = bf2f(u.z >> 16);
  f[6] = bf2f(u.w & 0xffffu); f[7] = bf2f(u.w >> 16);
}
// async global->LDS, 16B per lane; LDS dest = wave-uniform base + lane*16
static __device__ __forceinline__ void gl_lds16(const unsigned short* g,
                                                unsigned short* l) {
  __builtin_amdgcn_global_load_lds(
      (const __attribute__((address_space(1))) unsigned int*)g,
      (__attribute__((address_space(3))) unsigned int*)l, 16, 0, 0);
}

// Device-scope grid barrier (all blocks co-resident by construction).
static __device__ __forceinline__ void grid_barrier(unsigned* bar, unsigned target) {
  __syncthreads();
  if (threadIdx.x == 0) {
    __threadfence();  // release: prior global writes visible device-wide
    __hip_atomic_fetch_add(bar, 1u, __ATOMIC_ACQ_REL, __HIP_MEMORY_SCOPE_AGENT);
    while (__hip_atomic_load(bar, __ATOMIC_ACQUIRE, __HIP_MEMORY_SCOPE_AGENT) < target)
      __builtin_amdgcn_s_sleep(2);
  }
  __syncthreads();
}

// ---------------------------------------------------------------------------
// prep: grid-partitioned fusion of
//   [0,256)      conv_w      : W f32 -> Wbf bf16
//   [256,1280)   transpose_x : x f32 [b][k][i] -> xT bf16 [b][i][k]
//   [1280,1536)  softmax_c0  : c0[b][i][j] = softmax_j(b_init[b][j][i]) bf16
// Block 0 also zeroes the grid-barrier counter for route_all.
// ---------------------------------------------------------------------------
__global__ __launch_bounds__(256) void prep(
    const float* __restrict__ W, const float* __restrict__ x,
    const float* __restrict__ Binit,
    unsigned short* __restrict__ Wbf, unsigned short* __restrict__ xT,
    unsigned short* __restrict__ c0, unsigned* __restrict__ bar)
{
  __shared__ union {
    float Ls[64][65];   // transpose tile
    float Bs[64][68];   // softmax tile [j][ii]
  } sm;
  const int t   = threadIdx.x;
  const int blk = blockIdx.x;

  if (blk == 0 && t == 0) *bar = 0u;

  if (blk < 256) {
    // ---- conv_w ----
    const int g = blk * 256 + t;
    const float* s = W + (size_t)g * 8;
    f32x4 a = *(const f32x4*)s;
    f32x4 b = *(const f32x4*)(s + 4);
    uint4 o;
    o.x = (unsigned)f2bf(a.x) | ((unsigned)f2bf(a.y) << 16);
    o.y = (unsigned)f2bf(a.z) | ((unsigned)f2bf(a.w) << 16);
    o.z = (unsigned)f2bf(b.x) | ((unsigned)f2bf(b.y) << 16);
    o.w = (unsigned)f2bf(b.z) | ((unsigned)f2bf(b.w) << 16);
    *(uint4*)(Wbf + (size_t)g * 8) = o;
  } else if (blk < 1280) {
    // ---- transpose_x ----
    const int bid = blk - 256;
    const int i0  = (bid & 3) * 64;
    const int k0  = ((bid >> 2) & 3) * 64;
    const int b   = bid >> 4;
    for (int it = 0; it < 4; ++it) {
      const int k  = it * 16 + (t >> 4);
      const int i4 = (t & 15) * 4;
      f32x4 v = *(const f32x4*)(x + ((size_t)(b * KDIM + k0 + k) * ICAP) + i0 + i4);
      sm.Ls[k][i4 + 0] = v.x; sm.Ls[k][i4 + 1] = v.y;
      sm.Ls[k][i4 + 2] = v.z; sm.Ls[k][i4 + 3] = v.w;
    }
    __syncthreads();
    const int i  = t >> 2;
    const int kc = (t & 3) * 16;
    unsigned pk[8];
    for (int q = 0; q < 8; ++q) {
      float lo = sm.Ls[kc + 2 * q][i];
      float hi = sm.Ls[kc + 2 * q + 1][i];
      pk[q] = (unsigned)f2bf(lo) | ((unsigned)f2bf(hi) << 16);
    }
    unsigned short* dst = xT + ((size_t)(b * ICAP + i0 + i) * KDIM) + k0 + kc;
    uint4 s0; s0.x = pk[0]; s0.y = pk[1]; s0.z = pk[2]; s0.w = pk[3];
    uint4 s1; s1.x = pk[4]; s1.y = pk[5]; s1.z = pk[6]; s1.w = pk[7];
    *(uint4*)dst       = s0;
    *(uint4*)(dst + 8) = s1;
  } else {
    // ---- softmax_c0, 64x64 tile: block = (b, i-quarter) ----
    const int bid = blk - 1280;
    const int b   = bid >> 2;
    const int q   = bid & 3;
    {
      const int j  = t >> 2;
      const int c4 = (t & 3) * 16;
      const float* src = Binit + ((size_t)(b * JCAP + j) * ICAP) + q * 64 + c4;
      for (int r = 0; r < 4; ++r) {
        f32x4 v = *(const f32x4*)(src + r * 4);
        *(f32x4*)&sm.Bs[j][c4 + r * 4] = v;
      }
    }
    __syncthreads();
    if (t < 64) {
      const int ii = t;
      float m = -3.0e38f;
      for (int j = 0; j < 64; ++j) m = fmaxf(m, sm.Bs[j][ii]);
      float se = 0.f;
      for (int j = 0; j < 64; ++j) se += __expf(sm.Bs[j][ii] - m);
      const float inv = 1.0f / se;
      unsigned short* dst = c0 + ((size_t)(b * ICAP + q * 64 + ii) * JCAP);
      for (int qq = 0; qq < 8; ++qq) {
        unsigned pk[4];
        for (int h = 0; h < 4; ++h) {
          float lo = __expf(sm.Bs[qq * 8 + 2 * h][ii] - m) * inv;
          float hi = __expf(sm.Bs[qq * 8 + 2 * h + 1][ii] - m) * inv;
          pk[h] = (unsigned)f2bf(lo) | ((unsigned)f2bf(hi) << 16);
        }
        uint4 s; s.x = pk[0]; s.y = pk[1]; s.z = pk[2]; s.w = pk[3];
        *(uint4*)(dst + qq * 8) = s;
      }
    }
  }
}

// ---------------------------------------------------------------------------
// Kernel 1: P[b][i][o] = sum_k W[o][k]*x[b][k][i] + Wb[o]  (bf16 out)
// + fused routing-pass-0 s-accumulation into s0part using c0.
// ---------------------------------------------------------------------------
__global__ __launch_bounds__(256) void gemm_pred(
    const unsigned short* __restrict__ Wbf,  // [OUTD][KDIM] bf16
    const unsigned short* __restrict__ xT,   // [BS][ICAP][KDIM] bf16
    const float* __restrict__ Wb,            // [OUTD] f32
    const unsigned short* __restrict__ c0,   // [BS][ICAP][JCAP] bf16
    unsigned short* __restrict__ P,          // [BS][ICAP][OUTD] bf16
    float* __restrict__ s0part)              // [BS][4][OUTD] f32
{
  __shared__ union {
    unsigned short AB[2][128][64];           // swizzled, unpadded (32 KiB)
    struct {
      unsigned short C[128][136];            // [i][o] epilogue (272B stride)
      unsigned short c0t[128][4];            // c0 tile for this block's 4 j
    } ep;
  } sm;

  const int tid = threadIdx.x;
  const int b   = blockIdx.z;
  const int o0  = blockIdx.x * 128;
  const int i0  = blockIdx.y * 128;
  const int l   = tid & 63;
  const int m   = l & 15;
  const int w   = tid >> 6;
  const int wo  = (w & 1) * 64;
  const int wi  = (w >> 1) * 64;

  const int srow = l >> 3;
  const int gch  = (l & 7) ^ srow;

  f32x4 acc[4][4];
  for (int a = 0; a < 4; ++a)
    for (int c = 0; c < 4; ++c) acc[a][c] = (f32x4){0.f, 0.f, 0.f, 0.f};

  for (int r = 0; r < 4; ++r) {
    const int k0 = r * 64;
    __syncthreads();
    for (int c = 0; c < 4; ++c) {
      const int q   = w * 4 + c;
      const int row = q * 8 + srow;
      gl_lds16(Wbf + (size_t)(o0 + row) * KDIM + k0 + gch * 8,
               &sm.AB[0][q * 8][0]);
      gl_lds16(xT + ((size_t)(b * ICAP + i0 + row) * KDIM) + k0 + gch * 8,
               &sm.AB[1][q * 8][0]);
    }
    __syncthreads();
    for (int ks = 0; ks < 2; ++ks) {
      const int clog = ks * 4 + (l >> 4);
      bf16x8 af[4], bfg[4];
      for (int ti = 0; ti < 4; ++ti) {
        const int row = wo + 16 * ti + m;
        af[ti] = *(const bf16x8*)&sm.AB[0][row][(clog ^ (m & 7)) * 8];
      }
      for (int tj = 0; tj < 4; ++tj) {
        const int row = wi + 16 * tj + m;
        bfg[tj] = *(const bf16x8*)&sm.AB[1][row][(clog ^ (m & 7)) * 8];
      }
      for (int ti = 0; ti < 4; ++ti)
        for (int tj = 0; tj < 4; ++tj)
          acc[ti][tj] = __builtin_amdgcn_mfma_f32_16x16x32_bf16(
              af[ti], bfg[tj], acc[ti][tj], 0, 0, 0);
    }
  }

  __syncthreads();
  {
    const int q4 = (l >> 4) * 4;
    for (int ti = 0; ti < 4; ++ti) {
      const int ob = wo + 16 * ti + q4;
      f32x4 wb4 = *(const f32x4*)(Wb + o0 + ob);
      for (int tj = 0; tj < 4; ++tj) {
        const int ii = wi + 16 * tj + m;
        f32x4 a = acc[ti][tj];
        uint2 pk;
        pk.x = (unsigned)f2bf(a.x + wb4.x) | ((unsigned)f2bf(a.y + wb4.y) << 16);
        pk.y = (unsigned)f2bf(a.z + wb4.z) | ((unsigned)f2bf(a.w + wb4.w) << 16);
        *(uint2*)&sm.ep.C[ii][ob] = pk;
      }
    }
  }
  if (tid < 128) {
    const int j0 = blockIdx.x * 4;
    uint2 v = *(const uint2*)(c0 + ((size_t)(b * ICAP + i0 + tid) * JCAP) + j0);
    *(uint2*)&sm.ep.c0t[tid][0] = v;
  }
  __syncthreads();
  for (int rr = 0; rr < 8; ++rr) {
    const int id  = rr * 256 + tid;
    const int row = id >> 4;
    const int seg = id & 15;
    uint4 v = *(const uint4*)&sm.ep.C[row][seg * 8];
    *(uint4*)(P + ((size_t)(b * ICAP + i0 + row) * OUTD) + o0 + seg * 8) = v;
  }
  {
    const int oc = tid & 127;
    const int h  = tid >> 7;
    const int jj = oc >> 5;
    float s = 0.f;
    for (int ii = 0; ii < 64; ++ii) {
      const int i = h * 64 + ii;
      s += bf2f(sm.ep.C[i][oc]) * bf2f(sm.ep.c0t[i][jj]);
    }
    const int p = blockIdx.y * 2 + h;
    s0part[((size_t)(b * 4 + p) * OUTD) + o0 + oc] = s;
  }
}

// ---------------------------------------------------------------------------
// route_all phases
// ---------------------------------------------------------------------------
static __device__ __forceinline__ void squash0_phase(
    const float* __restrict__ s0part, float* __restrict__ V, int blk, int tid)
{
  const int l  = tid & 63;
  const int bj = blk * 4 + (tid >> 6);
  const int b  = bj >> 6;
  const int j  = bj & 63;
  const int d  = l & 31;
  const int h  = l >> 5;
  float s = 0.f;
  for (int p = h; p < 4; p += 2)
    s += s0part[((size_t)(b * 4 + p) * OUTD) + j * D2 + d];
  s += __shfl_xor(s, 32, 64);
  float sq = s * s;
  for (int off = 1; off < 32; off <<= 1) sq += __shfl_xor(sq, off, 64);
  float scale = (sq / (1.0f + sq)) / sqrtf(sq + 1e-8f);
  if (l < 32) V[(b * JCAP + j) * D2 + d] = scale * s;
}

static __device__ __forceinline__ void squash_phase(
    const unsigned short* __restrict__ partial, float* __restrict__ V,
    float* __restrict__ outp, int final_pass, int blk, int tid)
{
  const int l  = tid & 63;
  const int bj = blk * 4 + (tid >> 6);
  const int b  = bj >> 6;
  const int j  = bj & 63;
  const int d  = l & 31;
  const int h  = l >> 5;
  float s = 0.f;
  for (int p = h; p < PART; p += 2)
    s += bf2f(partial[((size_t)(b * PART + p) * OUTD) + j * D2 + d]);
  s += __shfl_xor(s, 32, 64);
  float sq = s * s;
  for (int off = 1; off < 32; off <<= 1) sq += __shfl_xor(sq, off, 64);
  float scale = (sq / (1.0f + sq)) / sqrtf(sq + 1e-8f);
  float v = scale * s;
  if (l < 32) {
    V[(b * JCAP + j) * D2 + d] = v;
    if (final_pass) outp[(b * JCAP + j) * D2 + d] = v;
  }
}

static __device__ __forceinline__ void route_phase(
    const unsigned short* __restrict__ P, const float* __restrict__ Binit,
    float* __restrict__ B1, const float* __restrict__ V,
    unsigned short* __restrict__ partial, int pass, int blk, int tid)
{
  const int l     = tid & 63;                  // j
  const int w     = tid >> 6;
  const int b     = blk >> 4;
  const int chunk = (blk & 15) * 4 + w;        // 0..63
  const int i0    = chunk * 4;

  float vv[32];
  {
    const float* vp = V + (b * JCAP + l) * D2;
    for (int q = 0; q < 8; ++q) {
      f32x4 t = *(const f32x4*)(vp + q * 4);
      vv[q*4+0] = t.x; vv[q*4+1] = t.y; vv[q*4+2] = t.z; vv[q*4+3] = t.w;
    }
  }
  float bold[4];
  if (pass == 1) {
    f32x4 t = *(const f32x4*)(Binit + (size_t)(b * JCAP + l) * ICAP + i0);
    bold[0] = t.x; bold[1] = t.y; bold[2] = t.z; bold[3] = t.w;
  } else {
    for (int ii = 0; ii < 4; ++ii)
      bold[ii] = B1[((size_t)(b * ICAP + i0 + ii)) * JCAP + l];
  }

  float sacc[32];
  for (int k = 0; k < 32; ++k) sacc[k] = 0.f;

  const unsigned short* pbase = P + ((size_t)(b * ICAP + i0) * OUTD) + l * D2;
  uint4 ubuf[2][4];
  for (int q = 0; q < 4; ++q) ubuf[0][q] = *(const uint4*)(pbase + q * 8);
  for (int q = 0; q < 4; ++q) ubuf[1][q] = *(const uint4*)(pbase + OUTD + q * 8);

#pragma unroll
  for (int ii = 0; ii < 4; ++ii) {
    uint4 cur[4];
    for (int q = 0; q < 4; ++q) cur[q] = ubuf[ii & 1][q];
    if (ii + 2 < 4)
      for (int q = 0; q < 4; ++q)
        ubuf[ii & 1][q] = *(const uint4*)(pbase + (size_t)(ii + 2) * OUTD + q * 8);

    float db = 0.f;
    for (int q = 0; q < 4; ++q) {
      float ps[8]; unpack8(cur[q], ps);
      for (int k = 0; k < 8; ++k) db += ps[k] * vv[q * 8 + k];
    }
    float bnew = bold[ii] + db;
    if (pass == 1) B1[((size_t)(b * ICAP + i0 + ii)) * JCAP + l] = bnew;

    float mx = bnew;
    for (int off = 1; off < 64; off <<= 1) mx = fmaxf(mx, __shfl_xor(mx, off, 64));
    float e = __expf(bnew - mx);
    float se = e;
    for (int off = 1; off < 64; off <<= 1) se += __shfl_xor(se, off, 64);
    float c = e / se;
    for (int q = 0; q < 4; ++q) {
      float ps[8]; unpack8(cur[q], ps);
      for (int k = 0; k < 8; ++k) sacc[q * 8 + k] += c * ps[k];
    }
  }

  unsigned short* pp = partial + ((size_t)(b * PART + chunk) * OUTD) + l * D2;
  for (int q = 0; q < 4; ++q) {
    uint4 o;
    o.x = (unsigned)f2bf(sacc[q*8+0]) | ((unsigned)f2bf(sacc[q*8+1]) << 16);
    o.y = (unsigned)f2bf(sacc[q*8+2]) | ((unsigned)f2bf(sacc[q*8+3]) << 16);
    o.z = (unsigned)f2bf(sacc[q*8+4]) | ((unsigned)f2bf(sacc[q*8+5]) << 16);
    o.w = (unsigned)f2bf(sacc[q*8+6]) | ((unsigned)f2bf(sacc[q*8+7]) << 16);
    *(uint4*)(pp + q * 8) = o;
  }
}

// route_all: squash0 | route1 | squash | route2 | squash, grid-barrier fused.
// 1024 blocks x 256 thr, launch_bounds(256,4) caps VGPR at 128 -> 4 blocks/CU
// guaranteed co-resident (capacity 2048 blocks >= grid 1024).
__global__ __launch_bounds__(256, 4) void route_all(
    const unsigned short* __restrict__ P, const float* __restrict__ Binit,
    float* __restrict__ B1, float* __restrict__ V,
    unsigned short* __restrict__ partial, const float* __restrict__ s0part,
    float* __restrict__ outp, unsigned* __restrict__ bar)
{
  const int blk = blockIdx.x;
  const int tid = threadIdx.x;

  squash0_phase(s0part, V, blk, tid);
  grid_barrier(bar, 1024u);
  route_phase(P, Binit, B1, V, partial, 1, blk, tid);
  grid_barrier(bar, 2048u);
  squash_phase(partial, V, nullptr, 0, blk, tid);
  grid_barrier(bar, 3072u);
  route_phase(P, Binit, B1, V, partial, 2, blk, tid);
  grid_barrier(bar, 4096u);
  squash_phase(partial, V, outp, 1, blk, tid);
}

// ---------------------------------------------------------------------------
extern "C" void kernel_launch(void* const* d_in, const int* in_sizes, int n_in,
                              void* d_out, int out_size, void* d_ws, size_t ws_size,
                              hipStream_t stream) {
  const float* x  = (const float*)d_in[0];
  const float* bi = (const float*)d_in[1];
  const float* W  = (const float*)d_in[2];
  const float* Wb = (const float*)d_in[3];
  float* out = (float*)d_out;

  char* ws = (char*)d_ws;
  const size_t MiB = 1024 * 1024;
  unsigned short* P       = (unsigned short*)ws;               // [0,64) MiB
  unsigned short* xT      = (unsigned short*)(ws + 64 * MiB);  // [64,72)
  unsigned short* Wbf     = (unsigned short*)(ws + 72 * MiB);  // [72,73)
  unsigned short* c0      = (unsigned short*)(ws + 76 * MiB);  // [76,78) bf16
  float*          s0part  = (float*)(ws + 78 * MiB);           // [78,80) f32
  unsigned short* partial = (unsigned short*)(ws + 64 * MiB);  // [64,80) overlay
  float* B1               = (float*)(ws + 80 * MiB);           // [80,84)
  float* V                = (float*)(ws + 84 * MiB);           // 0.5 MiB
  unsigned* bar           = (unsigned*)(ws + 85 * MiB);        // barrier counter

  prep<<<dim3(1536), 256, 0, stream>>>(W, x, bi, Wbf, xT, c0, bar);
  gemm_pred<<<dim3(16, 2, 64), 256, 0, stream>>>(Wbf, xT, Wb, c0, P, s0part);
  route_all<<<dim3(1024), 256, 0, stream>>>(P, bi, B1, V, partial, s0part, out, bar);
}

// Round 6
// 154.353 us; speedup vs baseline: 4.8091x; 4.8091x over previous
//
#include <hip/hip_runtime.h>
#include <hip/hip_bf16.h>

// Sizes fixed by the problem.
#define BS    64
#define KDIM  256   // in_dim
#define ICAP  256   // I = 16*16
#define JCAP  64    // J out-caps
#define D2    32
#define OUTD  2048  // J*D2
#define NPART 16    // partial rows per b from route passes (1 per block)

typedef short bf16x8 __attribute__((ext_vector_type(8)));
typedef float f32x4  __attribute__((ext_vector_type(4)));

static __device__ __forceinline__ float bf2f(unsigned u16) {
  union { unsigned u; float f; } v; v.u = u16 << 16; return v.f;
}
static __device__ __forceinline__ unsigned short f2bf(float x) {
  union { float f; unsigned u; } v; v.f = x;
  unsigned r = v.u + 0x7fffu + ((v.u >> 16) & 1u);
  return (unsigned short)(r >> 16);
}
static __device__ __forceinline__ void unpack8(uint4 u, float* f) {
  f[0] = bf2f(u.x & 0xffffu); f[1] = bf2f(u.x >> 16);
  f[2] = bf2f(u.y & 0xffffu); f[3] = bf2f(u.y >> 16);
  f[4] = bf2f(u.z & 0xffffu); f[5] = bf2f(u.z >> 16);
  f[6] = bf2f(u.w & 0xffffu); f[7] = bf2f(u.w >> 16);
}
// async global->LDS, 16B per lane; LDS dest = wave-uniform base + lane*16
static __device__ __forceinline__ void gl_lds16(const unsigned short* g,
                                                unsigned short* l) {
  __builtin_amdgcn_global_load_lds(
      (const __attribute__((address_space(1))) unsigned int*)g,
      (__attribute__((address_space(3))) unsigned int*)l, 16, 0, 0);
}

// ---------------------------------------------------------------------------
// prep: grid-partitioned fusion of
//   [0,256)      conv_w      : W f32 -> Wbf bf16
//   [256,1280)   transpose_x : x f32 [b][k][i] -> xT bf16 [b][i][k]
//   [1280,1536)  softmax_c0  : c0[b][i][j] = softmax_j(b_init[b][j][i]) bf16
// ---------------------------------------------------------------------------
__global__ __launch_bounds__(256) void prep(
    const float* __restrict__ W, const float* __restrict__ x,
    const float* __restrict__ Binit,
    unsigned short* __restrict__ Wbf, unsigned short* __restrict__ xT,
    unsigned short* __restrict__ c0)
{
  __shared__ union {
    float Ls[64][65];   // transpose tile
    float Bs[64][68];   // softmax tile [j][ii]
  } sm;
  const int t   = threadIdx.x;
  const int blk = blockIdx.x;

  if (blk < 256) {
    // ---- conv_w ----
    const int g = blk * 256 + t;
    const float* s = W + (size_t)g * 8;
    f32x4 a = *(const f32x4*)s;
    f32x4 b = *(const f32x4*)(s + 4);
    uint4 o;
    o.x = (unsigned)f2bf(a.x) | ((unsigned)f2bf(a.y) << 16);
    o.y = (unsigned)f2bf(a.z) | ((unsigned)f2bf(a.w) << 16);
    o.z = (unsigned)f2bf(b.x) | ((unsigned)f2bf(b.y) << 16);
    o.w = (unsigned)f2bf(b.z) | ((unsigned)f2bf(b.w) << 16);
    *(uint4*)(Wbf + (size_t)g * 8) = o;
  } else if (blk < 1280) {
    // ---- transpose_x ----
    const int bid = blk - 256;
    const int i0  = (bid & 3) * 64;
    const int k0  = ((bid >> 2) & 3) * 64;
    const int b   = bid >> 4;
    for (int it = 0; it < 4; ++it) {
      const int k  = it * 16 + (t >> 4);
      const int i4 = (t & 15) * 4;
      f32x4 v = *(const f32x4*)(x + ((size_t)(b * KDIM + k0 + k) * ICAP) + i0 + i4);
      sm.Ls[k][i4 + 0] = v.x; sm.Ls[k][i4 + 1] = v.y;
      sm.Ls[k][i4 + 2] = v.z; sm.Ls[k][i4 + 3] = v.w;
    }
    __syncthreads();
    const int i  = t >> 2;
    const int kc = (t & 3) * 16;
    unsigned pk[8];
    for (int q = 0; q < 8; ++q) {
      float lo = sm.Ls[kc + 2 * q][i];
      float hi = sm.Ls[kc + 2 * q + 1][i];
      pk[q] = (unsigned)f2bf(lo) | ((unsigned)f2bf(hi) << 16);
    }
    unsigned short* dst = xT + ((size_t)(b * ICAP + i0 + i) * KDIM) + k0 + kc;
    uint4 s0; s0.x = pk[0]; s0.y = pk[1]; s0.z = pk[2]; s0.w = pk[3];
    uint4 s1; s1.x = pk[4]; s1.y = pk[5]; s1.z = pk[6]; s1.w = pk[7];
    *(uint4*)dst       = s0;
    *(uint4*)(dst + 8) = s1;
  } else {
    // ---- softmax_c0, 64x64 tile: block = (b, i-quarter) ----
    const int bid = blk - 1280;
    const int b   = bid >> 2;
    const int q   = bid & 3;
    {
      const int j  = t >> 2;
      const int c4 = (t & 3) * 16;
      const float* src = Binit + ((size_t)(b * JCAP + j) * ICAP) + q * 64 + c4;
      for (int r = 0; r < 4; ++r) {
        f32x4 v = *(const f32x4*)(src + r * 4);
        *(f32x4*)&sm.Bs[j][c4 + r * 4] = v;
      }
    }
    __syncthreads();
    if (t < 64) {
      const int ii = t;
      float m = -3.0e38f;
      for (int j = 0; j < 64; ++j) m = fmaxf(m, sm.Bs[j][ii]);
      float se = 0.f;
      for (int j = 0; j < 64; ++j) se += __expf(sm.Bs[j][ii] - m);
      const float inv = 1.0f / se;
      unsigned short* dst = c0 + ((size_t)(b * ICAP + q * 64 + ii) * JCAP);
      for (int qq = 0; qq < 8; ++qq) {
        unsigned pk[4];
        for (int h = 0; h < 4; ++h) {
          float lo = __expf(sm.Bs[qq * 8 + 2 * h][ii] - m) * inv;
          float hi = __expf(sm.Bs[qq * 8 + 2 * h + 1][ii] - m) * inv;
          pk[h] = (unsigned)f2bf(lo) | ((unsigned)f2bf(hi) << 16);
        }
        uint4 s; s.x = pk[0]; s.y = pk[1]; s.z = pk[2]; s.w = pk[3];
        *(uint4*)(dst + qq * 8) = s;
      }
    }
  }
}

// ---------------------------------------------------------------------------
// Kernel 1: P[b][i][o] = sum_k W[o][k]*x[b][k][i] + Wb[o]  (bf16 out)
// + fused routing-pass-0 s-accumulation into s0part using c0.
// ---------------------------------------------------------------------------
__global__ __launch_bounds__(256) void gemm_pred(
    const unsigned short* __restrict__ Wbf,  // [OUTD][KDIM] bf16
    const unsigned short* __restrict__ xT,   // [BS][ICAP][KDIM] bf16
    const float* __restrict__ Wb,            // [OUTD] f32
    const unsigned short* __restrict__ c0,   // [BS][ICAP][JCAP] bf16
    unsigned short* __restrict__ P,          // [BS][ICAP][OUTD] bf16
    float* __restrict__ s0part)              // [BS][4][OUTD] f32
{
  __shared__ union {
    unsigned short AB[2][128][64];           // swizzled, unpadded (32 KiB)
    struct {
      unsigned short C[128][136];            // [i][o] epilogue (272B stride)
      unsigned short c0t[128][4];            // c0 tile for this block's 4 j
    } ep;
  } sm;

  const int tid = threadIdx.x;
  const int b   = blockIdx.z;
  const int o0  = blockIdx.x * 128;
  const int i0  = blockIdx.y * 128;
  const int l   = tid & 63;
  const int m   = l & 15;
  const int w   = tid >> 6;
  const int wo  = (w & 1) * 64;
  const int wi  = (w >> 1) * 64;

  const int srow = l >> 3;
  const int gch  = (l & 7) ^ srow;

  f32x4 acc[4][4];
  for (int a = 0; a < 4; ++a)
    for (int c = 0; c < 4; ++c) acc[a][c] = (f32x4){0.f, 0.f, 0.f, 0.f};

  for (int r = 0; r < 4; ++r) {
    const int k0 = r * 64;
    __syncthreads();
    for (int c = 0; c < 4; ++c) {
      const int q   = w * 4 + c;
      const int row = q * 8 + srow;
      gl_lds16(Wbf + (size_t)(o0 + row) * KDIM + k0 + gch * 8,
               &sm.AB[0][q * 8][0]);
      gl_lds16(xT + ((size_t)(b * ICAP + i0 + row) * KDIM) + k0 + gch * 8,
               &sm.AB[1][q * 8][0]);
    }
    __syncthreads();
    for (int ks = 0; ks < 2; ++ks) {
      const int clog = ks * 4 + (l >> 4);
      bf16x8 af[4], bfg[4];
      for (int ti = 0; ti < 4; ++ti) {
        const int row = wo + 16 * ti + m;
        af[ti] = *(const bf16x8*)&sm.AB[0][row][(clog ^ (m & 7)) * 8];
      }
      for (int tj = 0; tj < 4; ++tj) {
        const int row = wi + 16 * tj + m;
        bfg[tj] = *(const bf16x8*)&sm.AB[1][row][(clog ^ (m & 7)) * 8];
      }
      for (int ti = 0; ti < 4; ++ti)
        for (int tj = 0; tj < 4; ++tj)
          acc[ti][tj] = __builtin_amdgcn_mfma_f32_16x16x32_bf16(
              af[ti], bfg[tj], acc[ti][tj], 0, 0, 0);
    }
  }

  __syncthreads();
  {
    const int q4 = (l >> 4) * 4;
    for (int ti = 0; ti < 4; ++ti) {
      const int ob = wo + 16 * ti + q4;
      f32x4 wb4 = *(const f32x4*)(Wb + o0 + ob);
      for (int tj = 0; tj < 4; ++tj) {
        const int ii = wi + 16 * tj + m;
        f32x4 a = acc[ti][tj];
        uint2 pk;
        pk.x = (unsigned)f2bf(a.x + wb4.x) | ((unsigned)f2bf(a.y + wb4.y) << 16);
        pk.y = (unsigned)f2bf(a.z + wb4.z) | ((unsigned)f2bf(a.w + wb4.w) << 16);
        *(uint2*)&sm.ep.C[ii][ob] = pk;
      }
    }
  }
  if (tid < 128) {
    const int j0 = blockIdx.x * 4;
    uint2 v = *(const uint2*)(c0 + ((size_t)(b * ICAP + i0 + tid) * JCAP) + j0);
    *(uint2*)&sm.ep.c0t[tid][0] = v;
  }
  __syncthreads();
  for (int rr = 0; rr < 8; ++rr) {
    const int id  = rr * 256 + tid;
    const int row = id >> 4;
    const int seg = id & 15;
    uint4 v = *(const uint4*)&sm.ep.C[row][seg * 8];
    *(uint4*)(P + ((size_t)(b * ICAP + i0 + row) * OUTD) + o0 + seg * 8) = v;
  }
  {
    const int oc = tid & 127;
    const int h  = tid >> 7;
    const int jj = oc >> 5;
    float s = 0.f;
    for (int ii = 0; ii < 64; ++ii) {
      const int i = h * 64 + ii;
      s += bf2f(sm.ep.C[i][oc]) * bf2f(sm.ep.c0t[i][jj]);
    }
    const int p = blockIdx.y * 2 + h;
    s0part[((size_t)(b * 4 + p) * OUTD) + o0 + oc] = s;
  }
}

// ---------------------------------------------------------------------------
// route_fused: per-block redundant V-recompute (squash of part_in) + route
// phase + block-level s reduction -> part_out[b][g] (f32).
// Grid 1024 = (b, g); block g covers i in [g*16, g*16+16), wave w -> 4 i's.
// ---------------------------------------------------------------------------
__global__ __launch_bounds__(256) void route_fused(
    const unsigned short* __restrict__ P,     // [BS][ICAP][OUTD] bf16
    const float* __restrict__ Binit,          // [BS][JCAP][ICAP] f32
    float* __restrict__ B1,                   // [BS][ICAP][JCAP] f32
    const float* __restrict__ part_in,        // [BS][npart_in][OUTD] f32
    const int npart_in,
    float* __restrict__ part_out,             // [BS][NPART][OUTD] f32
    const int pass)
{
  __shared__ union {
    float Vs[2112];        // [j*33 + d], conflict-free
    float Ps[4][2112];     // per-wave s partials (Ps[0] aliases Vs)
  } sm;

  const int tid = threadIdx.x;
  const int l   = tid & 63;              // j in route phase
  const int w   = tid >> 6;
  const int b   = blockIdx.x >> 4;
  const int g   = blockIdx.x & 15;

  // ---- recompute V(b) = squash(sum part_in) ----
  {
    const float* base = part_in + (size_t)b * npart_in * OUTD + tid * 8;
    float s[8] = {0.f,0.f,0.f,0.f,0.f,0.f,0.f,0.f};
    for (int p = 0; p < npart_in; ++p) {
      f32x4 a = *(const f32x4*)(base + (size_t)p * OUTD);
      f32x4 c = *(const f32x4*)(base + (size_t)p * OUTD + 4);
      s[0] += a.x; s[1] += a.y; s[2] += a.z; s[3] += a.w;
      s[4] += c.x; s[5] += c.y; s[6] += c.z; s[7] += c.w;
    }
    float sq = 0.f;
    for (int c = 0; c < 8; ++c) sq += s[c] * s[c];
    sq += __shfl_xor(sq, 1, 64);
    sq += __shfl_xor(sq, 2, 64);          // norm over the 4-lane j-group
    float scale = (sq / (1.0f + sq)) / sqrtf(sq + 1e-8f);
    const int j  = tid >> 2;
    const int d0 = (tid & 3) * 8;
    for (int c = 0; c < 8; ++c) sm.Vs[j * 33 + d0 + c] = scale * s[c];
  }
  __syncthreads();
  float vv[32];
  for (int k = 0; k < 32; ++k) vv[k] = sm.Vs[l * 33 + k];

  // ---- route phase over this wave's 4 i ----
  const int i0 = g * 16 + w * 4;
  float bold[4];
  if (pass == 1) {
    f32x4 t = *(const f32x4*)(Binit + (size_t)(b * JCAP + l) * ICAP + i0);
    bold[0] = t.x; bold[1] = t.y; bold[2] = t.z; bold[3] = t.w;
  } else {
    for (int ii = 0; ii < 4; ++ii)
      bold[ii] = B1[((size_t)(b * ICAP + i0 + ii)) * JCAP + l];
  }

  float sacc[32];
  for (int k = 0; k < 32; ++k) sacc[k] = 0.f;

  const unsigned short* pbase = P + ((size_t)(b * ICAP + i0) * OUTD) + l * D2;
  uint4 ubuf[2][4];
  for (int q = 0; q < 4; ++q) ubuf[0][q] = *(const uint4*)(pbase + q * 8);
  for (int q = 0; q < 4; ++q) ubuf[1][q] = *(const uint4*)(pbase + OUTD + q * 8);

#pragma unroll
  for (int ii = 0; ii < 4; ++ii) {
    uint4 cur[4];
    for (int q = 0; q < 4; ++q) cur[q] = ubuf[ii & 1][q];
    if (ii + 2 < 4)
      for (int q = 0; q < 4; ++q)
        ubuf[ii & 1][q] = *(const uint4*)(pbase + (size_t)(ii + 2) * OUTD + q * 8);

    float db = 0.f;
    for (int q = 0; q < 4; ++q) {
      float ps[8]; unpack8(cur[q], ps);
      for (int k = 0; k < 8; ++k) db += ps[k] * vv[q * 8 + k];
    }
    float bnew = bold[ii] + db;
    if (pass == 1) B1[((size_t)(b * ICAP + i0 + ii)) * JCAP + l] = bnew;

    float mx = bnew;
    for (int off = 1; off < 64; off <<= 1) mx = fmaxf(mx, __shfl_xor(mx, off, 64));
    float e = __expf(bnew - mx);
    float se = e;
    for (int off = 1; off < 64; off <<= 1) se += __shfl_xor(se, off, 64);
    float c = e / se;
    for (int q = 0; q < 4; ++q) {
      float ps[8]; unpack8(cur[q], ps);
      for (int k = 0; k < 8; ++k) sacc[q * 8 + k] += c * ps[k];
    }
  }

  __syncthreads();   // Vs no longer needed; safe to overwrite via Ps
  for (int k = 0; k < 32; ++k) sm.Ps[w][l * 33 + k] = sacc[k];
  __syncthreads();

  // ---- block reduce 4 waves -> part_out[b][g] ----
  {
    const int o0 = tid * 8;
    float s[8];
    for (int c = 0; c < 8; ++c) {
      const int o = o0 + c, j = o >> 5, d = o & 31, idx = j * 33 + d;
      s[c] = sm.Ps[0][idx] + sm.Ps[1][idx] + sm.Ps[2][idx] + sm.Ps[3][idx];
    }
    float* dst = part_out + ((size_t)(b * NPART + g)) * OUTD + o0;
    f32x4 t0 = {s[0], s[1], s[2], s[3]};
    f32x4 t1 = {s[4], s[5], s[6], s[7]};
    *(f32x4*)dst       = t0;
    *(f32x4*)(dst + 4) = t1;
  }
}

// ---------------------------------------------------------------------------
// squash_final: reduce NPART partials, squash, write output. Block per b.
// ---------------------------------------------------------------------------
__global__ __launch_bounds__(256) void squash_final(
    const float* __restrict__ part,      // [BS][NPART][OUTD] f32
    float* __restrict__ outp)            // [BS][JCAP][D2] f32
{
  const int tid = threadIdx.x;
  const int b   = blockIdx.x;
  const float* base = part + (size_t)b * NPART * OUTD + tid * 8;
  float s[8] = {0.f,0.f,0.f,0.f,0.f,0.f,0.f,0.f};
  for (int p = 0; p < NPART; ++p) {
    f32x4 a = *(const f32x4*)(base + (size_t)p * OUTD);
    f32x4 c = *(const f32x4*)(base + (size_t)p * OUTD + 4);
    s[0] += a.x; s[1] += a.y; s[2] += a.z; s[3] += a.w;
    s[4] += c.x; s[5] += c.y; s[6] += c.z; s[7] += c.w;
  }
  float sq = 0.f;
  for (int c = 0; c < 8; ++c) sq += s[c] * s[c];
  sq += __shfl_xor(sq, 1, 64);
  sq += __shfl_xor(sq, 2, 64);
  float scale = (sq / (1.0f + sq)) / sqrtf(sq + 1e-8f);
  float* dst = outp + (size_t)b * OUTD + tid * 8;
  f32x4 t0 = {scale*s[0], scale*s[1], scale*s[2], scale*s[3]};
  f32x4 t1 = {scale*s[4], scale*s[5], scale*s[6], scale*s[7]};
  *(f32x4*)dst       = t0;
  *(f32x4*)(dst + 4) = t1;
}

// ---------------------------------------------------------------------------
extern "C" void kernel_launch(void* const* d_in, const int* in_sizes, int n_in,
                              void* d_out, int out_size, void* d_ws, size_t ws_size,
                              hipStream_t stream) {
  const float* x  = (const float*)d_in[0];
  const float* bi = (const float*)d_in[1];
  const float* W  = (const float*)d_in[2];
  const float* Wb = (const float*)d_in[3];
  float* out = (float*)d_out;

  char* ws = (char*)d_ws;
  const size_t MiB = 1024 * 1024;
  unsigned short* P        = (unsigned short*)ws;               // [0,64) MiB
  // lifetimes: xT dead after gemm -> partial1 overlays it; Wbf/c0/s0part dead
  // after route1 -> partial2 overlays them.
  unsigned short* xT       = (unsigned short*)(ws + 64 * MiB);  // [64,72)
  float*          partial1 = (float*)(ws + 64 * MiB);           // [64,72) overlay
  unsigned short* Wbf      = (unsigned short*)(ws + 72 * MiB);  // [72,73)
  unsigned short* c0       = (unsigned short*)(ws + 73 * MiB);  // [73,75)
  float*          s0part   = (float*)(ws + 75 * MiB);           // [75,77)
  float*          partial2 = (float*)(ws + 72 * MiB);           // [72,80) overlay
  float* B1                = (float*)(ws + 80 * MiB);           // [80,84)

  prep<<<dim3(1536), 256, 0, stream>>>(W, x, bi, Wbf, xT, c0);
  gemm_pred<<<dim3(16, 2, 64), 256, 0, stream>>>(Wbf, xT, Wb, c0, P, s0part);
  route_fused<<<dim3(1024), 256, 0, stream>>>(P, bi, B1, s0part, 4, partial1, 1);
  route_fused<<<dim3(1024), 256, 0, stream>>>(P, bi, B1, partial1, NPART, partial2, 2);
  squash_final<<<dim3(64), 256, 0, stream>>>(partial2, out);
}